// Round 4
// baseline (589.522 us; speedup 1.0000x reference)
//
#include <hip/hip_runtime.h>

#define EMB 768
#define NK  8192
#define NB  16384
#define NBLK 512            // NK/16 col-blocks
#define MARGIN 0.05f        // scaled-sim margin: ~20 sigma of bf16 screening error

typedef __attribute__((ext_vector_type(8))) __bf16 bf16x8;
typedef __attribute__((ext_vector_type(4))) float f32x4;

// ---------------- fp32 -> bf16 (RTNE) ----------------
__device__ __forceinline__ unsigned short f2bf(float f){
  unsigned u = __float_as_uint(f);
  u += 0x7FFFu + ((u >> 16) & 1u);
  return (unsigned short)(u >> 16);
}

// monotonic order-preserving float<->uint encoding
__device__ __forceinline__ unsigned fenc(float v){
  unsigned u = __float_as_uint(v);
  return (u & 0x80000000u) ? ~u : (u | 0x80000000u);
}
__device__ __forceinline__ float fdec(unsigned k){
  unsigned u = (k & 0x80000000u) ? (k & 0x7FFFFFFFu) : ~k;
  return __uint_as_float(u);
}

__global__ void convert_k(const float* __restrict__ in, unsigned short* __restrict__ out, int n4){
  int i = blockIdx.x * blockDim.x + threadIdx.x;
  if (i < n4){
    float4 v = *(const float4*)(in + (size_t)i * 4);
    ushort4 o;
    o.x = f2bf(v.x); o.y = f2bf(v.y); o.z = f2bf(v.z); o.w = f2bf(v.w);
    *(ushort4*)(out + (size_t)i * 4) = o;
  }
}

// ---------------- codebook inverse norms ----------------
__global__ void codebook_norms_k(const float* __restrict__ C, float* __restrict__ rn){
  __shared__ float red[256];
  const int r = blockIdx.x;
  const int tid = threadIdx.x;
  const float* row = C + (size_t)r * EMB;
  float s = 0.f;
  for (int c = tid; c < EMB; c += 256){ float v = row[c]; s = fmaf(v, v, s); }
  red[tid] = s; __syncthreads();
  for (int off = 128; off > 0; off >>= 1){
    if (tid < off) red[tid] += red[tid + off];
    __syncthreads();
  }
  if (tid == 0){
    float n = sqrtf(red[0]);
    rn[r] = 1.0f / fmaxf(n, 1e-8f);
  }
}

// stage one 16KB half-tile: 2 x global_load_lds(16B) per thread
#define STAGE2(p0_, p1_, k0_, d0_, d1_) do{ \
  __builtin_amdgcn_global_load_lds((const __attribute__((address_space(1))) void*)((p0_) + (k0_)), \
      (__attribute__((address_space(3))) void*)(lds + (d0_)), 16, 0, 0); \
  __builtin_amdgcn_global_load_lds((const __attribute__((address_space(1))) void*)((p1_) + (k0_)), \
      (__attribute__((address_space(3))) void*)(lds + (d1_)), 16, 0, 0); \
}while(0)

// ---------------- 256x256 8-phase bf16 MFMA GEMM -> blockmaxT + rowM ----------
// 8 waves (2m x 4n), BK=64, 2x64KB LDS double-buffer, counted-vmcnt pipeline.
// Phase p of tile t: {ds_read quadrant frags | stage one half-tile} ; barrier ;
// setprio(1) 16 MFMA setprio(0) ; [gate] ; barrier.
// Stage order: (t+1)h2(B-lo)@p0, (t+1)h3(A-hi)@p1, (t+1)h4(B-hi)@p2, (t+2)h1(A-lo)@p3.
// Gates: end-p0 vmcnt(4) (guarantees t.h4,h3 landed); end-p3 vmcnt(6) (guarantees
// (t+1).h1,h2 landed). Every LDS region has >=1 barrier between last read and rewrite.
__global__ __launch_bounds__(512, 2)
void gemm_bmax_k(const unsigned short* __restrict__ Xb, const unsigned short* __restrict__ Cbb,
                 const float* __restrict__ rn, float* __restrict__ blockmaxT,
                 unsigned* __restrict__ rowMkey){
  __shared__ __align__(16) char lds[131072];  // [2 bufs][A 32KB | B 32KB]
  const int tid  = threadIdx.x;
  const int lane = tid & 63;
  const int w    = tid >> 6;
  const int wm   = w >> 2, wn = w & 3;

  const int bid = blockIdx.x;
  const int swz = (bid & 7) * 256 + (bid >> 3);   // XCD-contiguous (2048 % 8 == 0)
  const int m0 = (swz >> 5) * 256;
  const int n0 = (swz & 31) * 256;

  // staging source addresses (per-thread, swizzle pre-applied to source)
  const int dr = lane >> 3;                 // row within 8-row chunk
  const int e  = ((lane & 7) ^ dr) << 3;    // element offset (XOR swizzle folded in)
  const unsigned short* aLo0 = Xb + (size_t)(m0 +       w*8 + dr) * EMB + e;
  const unsigned short* aLo1 = Xb + (size_t)(m0 + 128 + w*8 + dr) * EMB + e;
  const unsigned short* aHi0 = Xb + (size_t)(m0 +  64 + w*8 + dr) * EMB + e;
  const unsigned short* aHi1 = Xb + (size_t)(m0 + 192 + w*8 + dr) * EMB + e;
  const int Rb = (w >> 2)*64 + (w & 3)*8;
  const unsigned short* bLo0 = Cbb + (size_t)(n0 +       Rb + dr) * EMB + e;
  const unsigned short* bLo1 = Cbb + (size_t)(n0 + 128 + Rb + dr) * EMB + e;
  const unsigned short* bHi0 = Cbb + (size_t)(n0 +  32 + Rb + dr) * EMB + e;
  const unsigned short* bHi1 = Cbb + (size_t)(n0 + 160 + Rb + dr) * EMB + e;
  // LDS dests (wave-uniform, linear)
  const int dALo0 = w*1024,          dALo1 = 16384 + w*1024;
  const int dAHi0 = 8192 + w*1024,   dAHi1 = 24576 + w*1024;
  const int dB    = 32768 + (w >> 2)*8192 + (w & 3)*1024;
  const int dBLo0 = dB,              dBLo1 = dB + 16384;
  const int dBHi0 = dB + 4096,       dBHi1 = dB + 20480;

  f32x4 acc[8][4];
  #pragma unroll
  for (int m = 0; m < 8; ++m)
    #pragma unroll
    for (int n = 0; n < 4; ++n)
      acc[m][n] = (f32x4){0.f, 0.f, 0.f, 0.f};

  // prologue: tile0 all 4 halves -> buf0, tile1 h1 -> buf1
  STAGE2(aLo0, aLo1, 0, dALo0, dALo1);
  STAGE2(bLo0, bLo1, 0, dBLo0, dBLo1);
  STAGE2(aHi0, aHi1, 0, dAHi0, dAHi1);
  STAGE2(bHi0, bHi1, 0, dBHi0, dBHi1);
  STAGE2(aLo0, aLo1, 64, 65536 + dALo0, 65536 + dALo1);
  asm volatile("s_waitcnt vmcnt(4)" ::: "memory");   // tile0 h1,h2,h3 landed
  __builtin_amdgcn_s_barrier();

  bf16x8 afr[4][2], bfr[4][2];

#define LDA_FRAG(m_, kk_) { \
    const int ra = wm*128 + (m_)*16 + (lane & 15); \
    afr[(m_)&3][kk_] = *(const bf16x8*)(As + ra*128 + (((kk_)*64 + ((lane>>4)<<4)) ^ ((ra & 7) << 4))); }
#define LDB_FRAG(n_, kk_) { \
    const int rb = wn*64 + (n_)*16 + (lane & 15); \
    bfr[n_][kk_] = *(const bf16x8*)(Bs + rb*128 + (((kk_)*64 + ((lane>>4)<<4)) ^ ((rb & 7) << 4))); }

  for (int t = 0; t < 12; ++t){
    const int cb = (t & 1) << 16;
    const int nb = cb ^ 65536;
    const char* As = lds + cb;
    const char* Bs = As + 32768;
    const int k1 = (t + 1) * 64, k2 = (t + 2) * 64;

    // ---- p0: q1 = (m0-3) x (n0-1) ----
    #pragma unroll
    for (int m = 0; m < 4; ++m){ LDA_FRAG(m, 0); LDA_FRAG(m, 1); }
    #pragma unroll
    for (int n = 0; n < 2; ++n){ LDB_FRAG(n, 0); LDB_FRAG(n, 1); }
    if (t < 11) STAGE2(bLo0, bLo1, k1, nb + dBLo0, nb + dBLo1);
    __builtin_amdgcn_s_barrier();
    __builtin_amdgcn_s_setprio(1);
    #pragma unroll
    for (int m = 0; m < 4; ++m)
      #pragma unroll
      for (int n = 0; n < 2; ++n)
        #pragma unroll
        for (int kk = 0; kk < 2; ++kk)
          acc[m][n] = __builtin_amdgcn_mfma_f32_16x16x32_bf16(afr[m][kk], bfr[n][kk], acc[m][n], 0, 0, 0);
    __builtin_amdgcn_s_setprio(0);
    if (t < 11) asm volatile("s_waitcnt vmcnt(4)" ::: "memory");
    else        asm volatile("s_waitcnt vmcnt(0)" ::: "memory");
    __builtin_amdgcn_s_barrier();

    // ---- p1: q2 = (m0-3) x (n2-3) ----
    #pragma unroll
    for (int n = 2; n < 4; ++n){ LDB_FRAG(n, 0); LDB_FRAG(n, 1); }
    if (t < 11) STAGE2(aHi0, aHi1, k1, nb + dAHi0, nb + dAHi1);
    __builtin_amdgcn_s_barrier();
    __builtin_amdgcn_s_setprio(1);
    #pragma unroll
    for (int m = 0; m < 4; ++m)
      #pragma unroll
      for (int n = 2; n < 4; ++n)
        #pragma unroll
        for (int kk = 0; kk < 2; ++kk)
          acc[m][n] = __builtin_amdgcn_mfma_f32_16x16x32_bf16(afr[m][kk], bfr[n][kk], acc[m][n], 0, 0, 0);
    __builtin_amdgcn_s_setprio(0);
    __builtin_amdgcn_s_barrier();

    // ---- p2: q3 = (m4-7) x (n0-1) ----
    #pragma unroll
    for (int m = 4; m < 8; ++m){ LDA_FRAG(m, 0); LDA_FRAG(m, 1); }
    if (t < 11) STAGE2(bHi0, bHi1, k1, nb + dBHi0, nb + dBHi1);
    __builtin_amdgcn_s_barrier();
    __builtin_amdgcn_s_setprio(1);
    #pragma unroll
    for (int m = 0; m < 4; ++m)
      #pragma unroll
      for (int n = 0; n < 2; ++n)
        #pragma unroll
        for (int kk = 0; kk < 2; ++kk)
          acc[4 + m][n] = __builtin_amdgcn_mfma_f32_16x16x32_bf16(afr[m][kk], bfr[n][kk], acc[4 + m][n], 0, 0, 0);
    __builtin_amdgcn_s_setprio(0);
    __builtin_amdgcn_s_barrier();

    // ---- p3: q4 = (m4-7) x (n2-3) ----
    if (t < 10) STAGE2(aLo0, aLo1, k2, cb + dALo0, cb + dALo1);
    __builtin_amdgcn_s_barrier();
    __builtin_amdgcn_s_setprio(1);
    #pragma unroll
    for (int m = 0; m < 4; ++m)
      #pragma unroll
      for (int n = 2; n < 4; ++n)
        #pragma unroll
        for (int kk = 0; kk < 2; ++kk)
          acc[4 + m][n] = __builtin_amdgcn_mfma_f32_16x16x32_bf16(afr[m][kk], bfr[n][kk], acc[4 + m][n], 0, 0, 0);
    __builtin_amdgcn_s_setprio(0);
    if (t < 10)       asm volatile("s_waitcnt vmcnt(6)" ::: "memory");
    else if (t == 10) asm volatile("s_waitcnt vmcnt(4)" ::: "memory");
    __builtin_amdgcn_s_barrier();
  }
#undef LDA_FRAG
#undef LDB_FRAG

  // epilogue: scale by rn[col]; per-16col max -> blockmaxT[block][row]; rowM atomic
  float rnv[4];
  #pragma unroll
  for (int n = 0; n < 4; ++n) rnv[n] = rn[n0 + wn*64 + n*16 + (lane & 15)];
  const int rowb = m0 + wm*128 + ((lane >> 4) << 2);
  const int nbb  = (n0 + wn*64) >> 4;
  #pragma unroll
  for (int m = 0; m < 8; ++m){
    #pragma unroll
    for (int rg = 0; rg < 4; ++rg){
      const int grow = rowb + m*16 + rg;
      float wmax = -3.0e38f;
      #pragma unroll
      for (int n = 0; n < 4; ++n){
        float s = acc[m][n][rg] * rnv[n];
        #pragma unroll
        for (int off = 1; off < 16; off <<= 1) s = fmaxf(s, __shfl_xor(s, off));
        if ((lane & 15) == 0) blockmaxT[(size_t)(nbb + n) * NB + grow] = s;
        wmax = fmaxf(wmax, s);
      }
      if ((lane & 15) == 0) atomicMax(&rowMkey[grow], fenc(wmax));
    }
  }
}

// ---------------- codebook-stationary fp32 rescore ----------------
__global__ __launch_bounds__(256)
void rescore_k(const float* __restrict__ X, const float* __restrict__ Cb,
               const float* __restrict__ rn, const float* __restrict__ blockmaxT,
               const unsigned* __restrict__ rowMkey, unsigned long long* __restrict__ keys){
  __shared__ float cbs[16 * EMB];   // 48 KB
  __shared__ float rns[16];
  __shared__ int cand[1024];
  __shared__ int ncand;
  const int b = blockIdx.x;
  const int tid = threadIdx.x;
  const int lane = tid & 63;
  const int w = tid >> 6;

  for (int i = tid; i < 16 * EMB / 4; i += 256)
    ((float4*)cbs)[i] = ((const float4*)(Cb + (size_t)b * 16 * EMB))[i];
  if (tid < 16) rns[tid] = rn[b * 16 + tid];

  const float* bm = blockmaxT + (size_t)b * NB;
  for (int r0 = 0; r0 < NB; r0 += 1024){
    __syncthreads();
    if (tid == 0) ncand = 0;
    __syncthreads();
    #pragma unroll
    for (int k = 0; k < 4; ++k){
      const int r = r0 + k * 256 + tid;
      const float v = bm[r];
      const float M = fdec(rowMkey[r]);
      if (v >= M - MARGIN){
        int slot = atomicAdd(&ncand, 1);
        cand[slot] = r;
      }
    }
    __syncthreads();
    const int nc = ncand;
    for (int ci = w; ci < nc; ci += 4){
      const int r = cand[ci];
      const float* xr = X + (size_t)r * EMB;
      float x[12];
      #pragma unroll
      for (int j = 0; j < 12; ++j) x[j] = xr[lane + 64 * j];
      float best = -3.0e38f; int bc = 0;
      #pragma unroll
      for (int c = 0; c < 16; ++c){
        float s = 0.f;
        #pragma unroll
        for (int j = 0; j < 12; ++j) s = fmaf(x[j], cbs[c * EMB + lane + 64 * j], s);
        #pragma unroll
        for (int off = 1; off < 64; off <<= 1) s += __shfl_xor(s, off);
        s *= rns[c];
        if (s > best){ best = s; bc = c; }     // strict > : first index within block
      }
      if (lane == 0){
        const int col = b * 16 + bc;
        const unsigned long long key =
            ((unsigned long long)fenc(best) << 32) | (unsigned)(8191 - col);
        atomicMax(&keys[r], key);
      }
    }
  }
}

// ---------------- gather + output + per-row loss ----------------
__global__ void writer_k(const float* __restrict__ X, const float* __restrict__ Cb,
                         const unsigned long long* __restrict__ keys,
                         float* __restrict__ out, float* __restrict__ rowloss){
  __shared__ float red[256];
  const int r = blockIdx.x;
  const int tid = threadIdx.x;
  const int idx = 8191 - (int)(unsigned)(keys[r] & 0xFFFFFFFFull);
  const float* q = Cb + (size_t)idx * EMB;
  const float* x = X + (size_t)r * EMB;
  float* o = out + (size_t)r * EMB;
  float s = 0.f;
  for (int c = tid; c < EMB; c += 256){
    const float qv = q[c], xv = x[c];
    const float d = qv - xv;
    o[c] = xv + d;
    s = fmaf(d, d, s);
  }
  red[tid] = s; __syncthreads();
  for (int off = 128; off > 0; off >>= 1){
    if (tid < off) red[tid] += red[tid + off];
    __syncthreads();
  }
  if (tid == 0) rowloss[r] = red[0];
}

// ---------------- deterministic loss finalize ----------------
__global__ void finalize_k(const float* __restrict__ rowloss, float* __restrict__ loss_out){
  __shared__ double red[256];
  const int tid = threadIdx.x;
  double s = 0.0;
  for (int i = tid; i < NB; i += 256) s += (double)rowloss[i];
  red[tid] = s; __syncthreads();
  for (int off = 128; off > 0; off >>= 1){
    if (tid < off) red[tid] += red[tid + off];
    __syncthreads();
  }
  if (tid == 0)
    loss_out[0] = (float)(1.25 * red[0] / ((double)NB * (double)EMB));
}

extern "C" void kernel_launch(void* const* d_in, const int* in_sizes, int n_in,
                              void* d_out, int out_size, void* d_ws, size_t ws_size,
                              hipStream_t stream){
  const float* X  = (const float*)d_in[0];
  const float* Cb = (const float*)d_in[1];
  float* out = (float*)d_out;

  // bf16 staging copies live inside d_out (fully rewritten by writer_k later)
  unsigned short* Xb  = (unsigned short*)d_out;                              // 25.2 MB
  unsigned short* Cbb = (unsigned short*)((char*)d_out + (size_t)NB*EMB*2);  // 12.6 MB

  char* ws = (char*)d_ws;
  float* blockmaxT = (float*)ws;                                       // 33.55 MB
  char*  p = ws + (size_t)NBLK * NB * 4;
  unsigned* rowMkey = (unsigned*)p;            p += (size_t)NB * 4;    // 64 KB
  unsigned long long* keys = (unsigned long long*)p; p += (size_t)NB * 8; // 128 KB
  float* rn      = (float*)p;                  p += (size_t)NK * 4;    // 32 KB
  float* rowloss = (float*)p;                                          // 64 KB

  hipMemsetAsync(rowMkey, 0, (size_t)NB * 4, stream);
  hipMemsetAsync(keys, 0, (size_t)NB * 8, stream);
  convert_k<<<(NB * EMB / 4 + 255) / 256, 256, 0, stream>>>(X, Xb, NB * EMB / 4);
  convert_k<<<(NK * EMB / 4 + 255) / 256, 256, 0, stream>>>(Cb, Cbb, NK * EMB / 4);
  codebook_norms_k<<<NK, 256, 0, stream>>>(Cb, rn);
  gemm_bmax_k<<<2048, 512, 0, stream>>>(Xb, Cbb, rn, blockmaxT, rowMkey);
  rescore_k<<<NBLK, 256, 0, stream>>>(X, Cb, rn, blockmaxT, rowMkey, keys);
  writer_k<<<NB, 256, 0, stream>>>(X, Cb, keys, out, rowloss);
  finalize_k<<<1, 256, 0, stream>>>(rowloss, out + (size_t)NB * EMB);
}

// Round 5
// 518.602 us; speedup vs baseline: 1.1368x; 1.1368x over previous
//
#include <hip/hip_runtime.h>

#define EMB 768
#define NK  8192
#define NB  16384
#define NBLK 512            // NK/16 col-blocks
#define MARGIN 0.05f        // scaled-sim margin: ~20 sigma of bf16 screening error

typedef __attribute__((ext_vector_type(8))) __bf16 bf16x8;
typedef __attribute__((ext_vector_type(4))) float f32x4;

// ---------------- fp32 -> bf16 (RTNE) ----------------
__device__ __forceinline__ unsigned short f2bf(float f){
  unsigned u = __float_as_uint(f);
  u += 0x7FFFu + ((u >> 16) & 1u);
  return (unsigned short)(u >> 16);
}

// monotonic order-preserving float<->uint encoding
__device__ __forceinline__ unsigned fenc(float v){
  unsigned u = __float_as_uint(v);
  return (u & 0x80000000u) ? ~u : (u | 0x80000000u);
}
__device__ __forceinline__ float fdec(unsigned k){
  unsigned u = (k & 0x80000000u) ? (k & 0x7FFFFFFFu) : ~k;
  return __uint_as_float(u);
}

// convert X to bf16 + init rowMkey/keys (folds the two memsets)
__global__ void convert_x_k(const float* __restrict__ in, unsigned short* __restrict__ out,
                            unsigned* __restrict__ rowMkey, unsigned long long* __restrict__ keys){
  int i = blockIdx.x * blockDim.x + threadIdx.x;
  float4 v = *(const float4*)(in + (size_t)i * 4);
  ushort4 o;
  o.x = f2bf(v.x); o.y = f2bf(v.y); o.z = f2bf(v.z); o.w = f2bf(v.w);
  *(ushort4*)(out + (size_t)i * 4) = o;
  if (i < NB){ rowMkey[i] = 0u; keys[i] = 0ull; }
}

// convert Cb to bf16 + inverse norms in one read
__global__ __launch_bounds__(256)
void convert_cb_k(const float* __restrict__ C, unsigned short* __restrict__ Cbb,
                  float* __restrict__ rn){
  __shared__ float red[256];
  const int r = blockIdx.x;
  const int tid = threadIdx.x;
  float s = 0.f;
  if (tid < 192){
    const float4 v = ((const float4*)(C + (size_t)r * EMB))[tid];
    s = fmaf(v.x, v.x, fmaf(v.y, v.y, fmaf(v.z, v.z, v.w * v.w)));
    ushort4 o;
    o.x = f2bf(v.x); o.y = f2bf(v.y); o.z = f2bf(v.z); o.w = f2bf(v.w);
    ((ushort4*)(Cbb + (size_t)r * EMB))[tid] = o;
  }
  red[tid] = s; __syncthreads();
  for (int off = 128; off > 0; off >>= 1){
    if (tid < off) red[tid] += red[tid + off];
    __syncthreads();
  }
  if (tid == 0) rn[r] = 1.0f / fmaxf(sqrtf(red[0]), 1e-8f);
}

// stage one 16KB half-tile: 2 x global_load_lds(16B) per thread
#define STAGE2(p0_, p1_, k0_, d0_, d1_) do{ \
  __builtin_amdgcn_global_load_lds((const __attribute__((address_space(1))) void*)((p0_) + (k0_)), \
      (__attribute__((address_space(3))) void*)(lds + (d0_)), 16, 0, 0); \
  __builtin_amdgcn_global_load_lds((const __attribute__((address_space(1))) void*)((p1_) + (k0_)), \
      (__attribute__((address_space(3))) void*)(lds + (d1_)), 16, 0, 0); \
}while(0)

// ---------------- 256x256 8-phase bf16 MFMA GEMM -> blockmaxT + rowM ----------
// Same verified counted-vmcnt ledger as r4. Changed: XCD block mapping keeps each
// XCD's resident working set (4 B-panels + 8 A-panels ~ 4.7MB) L2-resident.
__global__ __launch_bounds__(512, 2)
void gemm_bmax_k(const unsigned short* __restrict__ Xb, const unsigned short* __restrict__ Cbb,
                 const float* __restrict__ rn, float* __restrict__ blockmaxT,
                 unsigned* __restrict__ rowMkey){
  __shared__ __align__(16) char lds[131072];  // [2 bufs][A 32KB | B 32KB]
  const int tid  = threadIdx.x;
  const int lane = tid & 63;
  const int w    = tid >> 6;
  const int wm   = w >> 2, wn = w & 3;

  const int bid = blockIdx.x;
  const int xcd = bid & 7;
  const int kb  = bid >> 3;                 // 0..255 sequential within XCD
  const int m0  = (xcd * 8 + (kb & 7)) * 256;   // m partitioned per XCD, fastest
  const int n0  = (kb >> 3) * 256;              // n advances every 8 blocks

  // staging source addresses (per-thread, swizzle pre-applied to source)
  const int dr = lane >> 3;                 // row within 8-row chunk
  const int e  = ((lane & 7) ^ dr) << 3;    // element offset (XOR swizzle folded in)
  const unsigned short* aLo0 = Xb + (size_t)(m0 +       w*8 + dr) * EMB + e;
  const unsigned short* aLo1 = Xb + (size_t)(m0 + 128 + w*8 + dr) * EMB + e;
  const unsigned short* aHi0 = Xb + (size_t)(m0 +  64 + w*8 + dr) * EMB + e;
  const unsigned short* aHi1 = Xb + (size_t)(m0 + 192 + w*8 + dr) * EMB + e;
  const int Rb = (w >> 2)*64 + (w & 3)*8;
  const unsigned short* bLo0 = Cbb + (size_t)(n0 +       Rb + dr) * EMB + e;
  const unsigned short* bLo1 = Cbb + (size_t)(n0 + 128 + Rb + dr) * EMB + e;
  const unsigned short* bHi0 = Cbb + (size_t)(n0 +  32 + Rb + dr) * EMB + e;
  const unsigned short* bHi1 = Cbb + (size_t)(n0 + 160 + Rb + dr) * EMB + e;
  // LDS dests (wave-uniform, linear)
  const int dALo0 = w*1024,          dALo1 = 16384 + w*1024;
  const int dAHi0 = 8192 + w*1024,   dAHi1 = 24576 + w*1024;
  const int dB    = 32768 + (w >> 2)*8192 + (w & 3)*1024;
  const int dBLo0 = dB,              dBLo1 = dB + 16384;
  const int dBHi0 = dB + 4096,       dBHi1 = dB + 20480;

  f32x4 acc[8][4];
  #pragma unroll
  for (int m = 0; m < 8; ++m)
    #pragma unroll
    for (int n = 0; n < 4; ++n)
      acc[m][n] = (f32x4){0.f, 0.f, 0.f, 0.f};

  // prologue: tile0 all 4 halves -> buf0, tile1 h1 -> buf1
  STAGE2(aLo0, aLo1, 0, dALo0, dALo1);
  STAGE2(bLo0, bLo1, 0, dBLo0, dBLo1);
  STAGE2(aHi0, aHi1, 0, dAHi0, dAHi1);
  STAGE2(bHi0, bHi1, 0, dBHi0, dBHi1);
  STAGE2(aLo0, aLo1, 64, 65536 + dALo0, 65536 + dALo1);
  asm volatile("s_waitcnt vmcnt(4)" ::: "memory");   // tile0 h1,h2,h3 landed
  __builtin_amdgcn_s_barrier();

  bf16x8 afr[4][2], bfr[4][2];

#define LDA_FRAG(m_, kk_) { \
    const int ra = wm*128 + (m_)*16 + (lane & 15); \
    afr[(m_)&3][kk_] = *(const bf16x8*)(As + ra*128 + (((kk_)*64 + ((lane>>4)<<4)) ^ ((ra & 7) << 4))); }
#define LDB_FRAG(n_, kk_) { \
    const int rb = wn*64 + (n_)*16 + (lane & 15); \
    bfr[n_][kk_] = *(const bf16x8*)(Bs + rb*128 + (((kk_)*64 + ((lane>>4)<<4)) ^ ((rb & 7) << 4))); }

  for (int t = 0; t < 12; ++t){
    const int cb = (t & 1) << 16;
    const int nb = cb ^ 65536;
    const char* As = lds + cb;
    const char* Bs = As + 32768;
    const int k1 = (t + 1) * 64, k2 = (t + 2) * 64;

    // ---- p0: q1 = (m0-3) x (n0-1) ----
    #pragma unroll
    for (int m = 0; m < 4; ++m){ LDA_FRAG(m, 0); LDA_FRAG(m, 1); }
    #pragma unroll
    for (int n = 0; n < 2; ++n){ LDB_FRAG(n, 0); LDB_FRAG(n, 1); }
    if (t < 11) STAGE2(bLo0, bLo1, k1, nb + dBLo0, nb + dBLo1);
    __builtin_amdgcn_s_barrier();
    __builtin_amdgcn_s_setprio(1);
    #pragma unroll
    for (int m = 0; m < 4; ++m)
      #pragma unroll
      for (int n = 0; n < 2; ++n)
        #pragma unroll
        for (int kk = 0; kk < 2; ++kk)
          acc[m][n] = __builtin_amdgcn_mfma_f32_16x16x32_bf16(afr[m][kk], bfr[n][kk], acc[m][n], 0, 0, 0);
    __builtin_amdgcn_s_setprio(0);
    if (t < 11) asm volatile("s_waitcnt vmcnt(4)" ::: "memory");
    else        asm volatile("s_waitcnt vmcnt(0)" ::: "memory");
    __builtin_amdgcn_s_barrier();

    // ---- p1: q2 = (m0-3) x (n2-3) ----
    #pragma unroll
    for (int n = 2; n < 4; ++n){ LDB_FRAG(n, 0); LDB_FRAG(n, 1); }
    if (t < 11) STAGE2(aHi0, aHi1, k1, nb + dAHi0, nb + dAHi1);
    __builtin_amdgcn_s_barrier();
    __builtin_amdgcn_s_setprio(1);
    #pragma unroll
    for (int m = 0; m < 4; ++m)
      #pragma unroll
      for (int n = 2; n < 4; ++n)
        #pragma unroll
        for (int kk = 0; kk < 2; ++kk)
          acc[m][n] = __builtin_amdgcn_mfma_f32_16x16x32_bf16(afr[m][kk], bfr[n][kk], acc[m][n], 0, 0, 0);
    __builtin_amdgcn_s_setprio(0);
    __builtin_amdgcn_s_barrier();

    // ---- p2: q3 = (m4-7) x (n0-1) ----
    #pragma unroll
    for (int m = 4; m < 8; ++m){ LDA_FRAG(m, 0); LDA_FRAG(m, 1); }
    if (t < 11) STAGE2(bHi0, bHi1, k1, nb + dBHi0, nb + dBHi1);
    __builtin_amdgcn_s_barrier();
    __builtin_amdgcn_s_setprio(1);
    #pragma unroll
    for (int m = 0; m < 4; ++m)
      #pragma unroll
      for (int n = 0; n < 2; ++n)
        #pragma unroll
        for (int kk = 0; kk < 2; ++kk)
          acc[4 + m][n] = __builtin_amdgcn_mfma_f32_16x16x32_bf16(afr[m][kk], bfr[n][kk], acc[4 + m][n], 0, 0, 0);
    __builtin_amdgcn_s_setprio(0);
    __builtin_amdgcn_s_barrier();

    // ---- p3: q4 = (m4-7) x (n2-3) ----
    if (t < 10) STAGE2(aLo0, aLo1, k2, cb + dALo0, cb + dALo1);
    __builtin_amdgcn_s_barrier();
    __builtin_amdgcn_s_setprio(1);
    #pragma unroll
    for (int m = 0; m < 4; ++m)
      #pragma unroll
      for (int n = 2; n < 4; ++n)
        #pragma unroll
        for (int kk = 0; kk < 2; ++kk)
          acc[4 + m][n] = __builtin_amdgcn_mfma_f32_16x16x32_bf16(afr[m][kk], bfr[n][kk], acc[4 + m][n], 0, 0, 0);
    __builtin_amdgcn_s_setprio(0);
    if (t < 10)       asm volatile("s_waitcnt vmcnt(6)" ::: "memory");
    else if (t == 10) asm volatile("s_waitcnt vmcnt(4)" ::: "memory");
    __builtin_amdgcn_s_barrier();
  }
#undef LDA_FRAG
#undef LDB_FRAG

  // epilogue: scale by rn[col]; per-16col max -> blockmaxT[block][row]; rowM atomic
  float rnv[4];
  #pragma unroll
  for (int n = 0; n < 4; ++n) rnv[n] = rn[n0 + wn*64 + n*16 + (lane & 15)];
  const int rowb = m0 + wm*128 + ((lane >> 4) << 2);
  const int nbb  = (n0 + wn*64) >> 4;
  #pragma unroll
  for (int m = 0; m < 8; ++m){
    #pragma unroll
    for (int rg = 0; rg < 4; ++rg){
      const int grow = rowb + m*16 + rg;
      float wmax = -3.0e38f;
      #pragma unroll
      for (int n = 0; n < 4; ++n){
        float s = acc[m][n][rg] * rnv[n];
        #pragma unroll
        for (int off = 1; off < 16; off <<= 1) s = fmaxf(s, __shfl_xor(s, off));
        if ((lane & 15) == 0) blockmaxT[(size_t)(nbb + n) * NB + grow] = s;
        wmax = fmaxf(wmax, s);
      }
      if ((lane & 15) == 0) atomicMax(&rowMkey[grow], fenc(wmax));
    }
  }
}

// ---------------- codebook-stationary fp32 rescore ----------------
__global__ __launch_bounds__(256)
void rescore_k(const float* __restrict__ X, const float* __restrict__ Cb,
               const float* __restrict__ rn, const float* __restrict__ blockmaxT,
               const unsigned* __restrict__ rowMkey, unsigned long long* __restrict__ keys){
  __shared__ float cbs[16 * EMB];   // 48 KB
  __shared__ float rns[16];
  __shared__ int cand[1024];
  __shared__ int ncand;
  const int b = blockIdx.x;
  const int tid = threadIdx.x;
  const int lane = tid & 63;
  const int w = tid >> 6;

  for (int i = tid; i < 16 * EMB / 4; i += 256)
    ((float4*)cbs)[i] = ((const float4*)(Cb + (size_t)b * 16 * EMB))[i];
  if (tid < 16) rns[tid] = rn[b * 16 + tid];

  const float* bm = blockmaxT + (size_t)b * NB;
  for (int r0 = 0; r0 < NB; r0 += 1024){
    __syncthreads();
    if (tid == 0) ncand = 0;
    __syncthreads();
    #pragma unroll
    for (int k = 0; k < 4; ++k){
      const int r = r0 + k * 256 + tid;
      const float v = bm[r];
      const float M = fdec(rowMkey[r]);
      if (v >= M - MARGIN){
        int slot = atomicAdd(&ncand, 1);
        cand[slot] = r;
      }
    }
    __syncthreads();
    const int nc = ncand;
    for (int ci = w; ci < nc; ci += 4){
      const int r = cand[ci];
      const float* xr = X + (size_t)r * EMB;
      float x[12];
      #pragma unroll
      for (int j = 0; j < 12; ++j) x[j] = xr[lane + 64 * j];
      float best = -3.0e38f; int bc = 0;
      #pragma unroll
      for (int c = 0; c < 16; ++c){
        float s = 0.f;
        #pragma unroll
        for (int j = 0; j < 12; ++j) s = fmaf(x[j], cbs[c * EMB + lane + 64 * j], s);
        #pragma unroll
        for (int off = 1; off < 64; off <<= 1) s += __shfl_xor(s, off);
        s *= rns[c];
        if (s > best){ best = s; bc = c; }     // strict > : first index within block
      }
      if (lane == 0){
        const int col = b * 16 + bc;
        const unsigned long long key =
            ((unsigned long long)fenc(best) << 32) | (unsigned)(8191 - col);
        atomicMax(&keys[r], key);
      }
    }
  }
}

// ---------------- gather + output + per-row loss (one wave per row) ----------
__global__ __launch_bounds__(256)
void writer_k(const float* __restrict__ X, const float* __restrict__ Cb,
              const unsigned long long* __restrict__ keys,
              float* __restrict__ out, float* __restrict__ rowloss){
  const int r    = (blockIdx.x * 256 + threadIdx.x) >> 6;   // one wave per row
  const int lane = threadIdx.x & 63;
  const int idx = 8191 - (int)(unsigned)(keys[r] & 0xFFFFFFFFull);
  const float4* q = (const float4*)(Cb + (size_t)idx * EMB);
  const float4* x = (const float4*)(X + (size_t)r * EMB);
  float4* o = (float4*)(out + (size_t)r * EMB);
  float s = 0.f;
  #pragma unroll
  for (int j = 0; j < 3; ++j){
    const float4 qv = q[lane + 64 * j];
    const float4 xv = x[lane + 64 * j];
    float4 ov;
    float dx = qv.x - xv.x, dy = qv.y - xv.y, dz = qv.z - xv.z, dw = qv.w - xv.w;
    ov.x = xv.x + dx; ov.y = xv.y + dy; ov.z = xv.z + dz; ov.w = xv.w + dw;
    o[lane + 64 * j] = ov;
    s = fmaf(dx, dx, fmaf(dy, dy, fmaf(dz, dz, fmaf(dw, dw, s))));
  }
  #pragma unroll
  for (int off = 1; off < 64; off <<= 1) s += __shfl_xor(s, off);
  if (lane == 0) rowloss[r] = s;
}

// ---------------- deterministic loss finalize ----------------
__global__ void finalize_k(const float* __restrict__ rowloss, float* __restrict__ loss_out){
  __shared__ double red[256];
  const int tid = threadIdx.x;
  double s = 0.0;
  for (int i = tid; i < NB; i += 256) s += (double)rowloss[i];
  red[tid] = s; __syncthreads();
  for (int off = 128; off > 0; off >>= 1){
    if (tid < off) red[tid] += red[tid + off];
    __syncthreads();
  }
  if (tid == 0)
    loss_out[0] = (float)(1.25 * red[0] / ((double)NB * (double)EMB));
}

extern "C" void kernel_launch(void* const* d_in, const int* in_sizes, int n_in,
                              void* d_out, int out_size, void* d_ws, size_t ws_size,
                              hipStream_t stream){
  const float* X  = (const float*)d_in[0];
  const float* Cb = (const float*)d_in[1];
  float* out = (float*)d_out;

  // bf16 staging copies live inside d_out (fully rewritten by writer_k later)
  unsigned short* Xb  = (unsigned short*)d_out;                              // 25.2 MB
  unsigned short* Cbb = (unsigned short*)((char*)d_out + (size_t)NB*EMB*2);  // 12.6 MB

  char* ws = (char*)d_ws;
  float* blockmaxT = (float*)ws;                                       // 33.55 MB
  char*  p = ws + (size_t)NBLK * NB * 4;
  unsigned* rowMkey = (unsigned*)p;            p += (size_t)NB * 4;    // 64 KB
  unsigned long long* keys = (unsigned long long*)p; p += (size_t)NB * 8; // 128 KB
  float* rn      = (float*)p;                  p += (size_t)NK * 4;    // 32 KB
  float* rowloss = (float*)p;                                          // 64 KB

  convert_x_k<<<NB * EMB / 4 / 256, 256, 0, stream>>>(X, Xb, rowMkey, keys);
  convert_cb_k<<<NK, 256, 0, stream>>>(Cb, Cbb, rn);
  gemm_bmax_k<<<2048, 512, 0, stream>>>(Xb, Cbb, rn, blockmaxT, rowMkey);
  rescore_k<<<NBLK, 256, 0, stream>>>(X, Cb, rn, blockmaxT, rowMkey, keys);
  writer_k<<<NB / 4, 256, 0, stream>>>(X, Cb, keys, out, rowloss);
  finalize_k<<<1, 256, 0, stream>>>(rowloss, out + (size_t)NB * EMB);
}